// Round 4
// baseline (177.282 us; speedup 1.0000x reference)
//
#include <hip/hip_runtime.h>
#include <hip/hip_cooperative_groups.h>
#include <cfloat>
#include <cstdint>

namespace cg = cooperative_groups;

// Problem constants (match reference)
constexpr int B = 32, H = 24, L = 800, T = 200;
constexpr int ROWS = B * H * L;      // 614400
constexpr int GRID = 768;            // 3 blocks/CU exactly; 800 rows per block
constexpr int TPB = 50;              // tasks per block (16 rows per task)
constexpr int F4_ROW = T / 4;        // 50 float4 per row

typedef float v4f __attribute__((ext_vector_type(4)));

__device__ inline v4f ntl(const v4f* p) { return __builtin_nontemporal_load(p); }

__device__ inline void upd(float v, int t, int ilen,
                           float& rmax, float& bv, int& bi) {
    rmax = fmaxf(rmax, v);
    // values are uniform [0,1) -> -1.0f is a safe "-inf" sentinel; every lane's
    // first float4 is at t<64<=ilen so bv ends >=0 and sentinels never win.
    const float vm = (t < ilen) ? v : -1.0f;
    if (vm > bv) { bv = vm; bi = t; }   // strict '>' + increasing t = first occurrence
}

__device__ inline void upd4(const v4f v, int t0, int ilen,
                            float& rmax, float& bv, int& bi) {
    upd(v.x, t0 + 0, ilen, rmax, bv, bi);
    upd(v.y, t0 + 1, ilen, rmax, bv, bi);
    upd(v.z, t0 + 2, ilen, rmax, bv, bi);
    upd(v.w, t0 + 3, ilen, rmax, bv, bi);
}

// Each block covers rows [bid*800, bid*800+800) -> exactly one (b, h):
//   b = bid / 24, h = bid % 24. ilen is block-uniform.
__device__ __forceinline__ void rowscan_body(const float* __restrict__ att,
                                             const int* __restrict__ ilens,
                                             uint8_t* __restrict__ amax,
                                             double* __restrict__ partial,
                                             double* sh) {
    const int tid = threadIdx.x;
    const int grp = tid >> 4;          // 16 groups (rows) per task
    const int j   = tid & 15;          // lane within group
    const int bid = blockIdx.x;
    const int b   = bid / H;           // block-uniform batch
    const int ilen = ilens[b];         // scalar

    const int row0 = bid * 800 + grp;
    const v4f* p = (const v4f*)att + (size_t)row0 * F4_ROW;

    double acc = 0.0;                  // group leaders (j==0) only

    // prefetch task 0
    v4f c0 = ntl(p + j), c1 = ntl(p + j + 16), c2 = ntl(p + j + 32), c3{};
    if (j < 2) c3 = ntl(p + 48 + j);

    #pragma unroll 2
    for (int it = 0; it < TPB; ++it) {
        const v4f* pn = p + 16 * F4_ROW;
        v4f n0{}, n1{}, n2{}, n3{};
        if (it + 1 < TPB) {            // prefetch next task
            n0 = ntl(pn + j); n1 = ntl(pn + j + 16); n2 = ntl(pn + j + 32);
            if (j < 2) n3 = ntl(pn + 48 + j);
        }

        float rmax = -FLT_MAX, bv = -FLT_MAX;
        int bi = 0;
        upd4(c0, 4 * j,       ilen, rmax, bv, bi);
        upd4(c1, 4 * j + 64,  ilen, rmax, bv, bi);
        upd4(c2, 4 * j + 128, ilen, rmax, bv, bi);
        if (j < 2) upd4(c3, 192 + 4 * j, ilen, rmax, bv, bi);

        // reduce within the 16-lane group
        #pragma unroll
        for (int off = 8; off >= 1; off >>= 1) {
            const float ov = __shfl_xor(bv, off);
            const int   oi = __shfl_xor(bi, off);
            rmax = fmaxf(rmax, __shfl_xor(rmax, off));
            if (ov > bv || (ov == bv && oi < bi)) { bv = ov; bi = oi; }
        }

        if (j == 0) {
            amax[row0 + it * 16] = (uint8_t)bi;
            acc += (double)rmax;
        }

        c0 = n0; c1 = n1; c2 = n2; c3 = n3;
        p = pn;
    }

    // block reduce: 16 group-leader accs, fixed order -> deterministic
    if (j == 0) sh[grp] = acc;
    __syncthreads();
    if (tid == 0) {
        double s = 0.0;
        #pragma unroll
        for (int i = 0; i < 16; ++i) s += sh[i];
        partial[bid] = s;
    }
}

// Head selection (fixed-tree reduce over 768 partials, deterministic) +
// per-batch LDS histogram for batch element b.
__device__ __forceinline__ void final_body(const uint8_t* __restrict__ amax,
                                           const int* __restrict__ olens,
                                           const double* __restrict__ partial,
                                           int* __restrict__ out, int b,
                                           double* shd, int* s_head, int* hist) {
    const int tid = threadIdx.x;

    if (tid < 192) {                   // 8 threads per head
        const int h = tid >> 3, k = tid & 7;
        double s = 0.0;
        #pragma unroll
        for (int m = 0; m < 4; ++m)
            s += partial[(size_t)(k * 4 + m) * H + h];   // partial[bb*24 + h]
        s += __shfl_xor(s, 1);
        s += __shfl_xor(s, 2);
        s += __shfl_xor(s, 4);
        if (k == 0) shd[h] = s;
    }
    for (int t = tid; t < T; t += 256) hist[t] = 0;
    __syncthreads();

    if (tid == 0) {
        double best = shd[0]; int bh = 0;
        for (int h = 1; h < H; ++h)
            if (shd[h] > best) { best = shd[h]; bh = h; }
        *s_head = bh;
    }
    __syncthreads();

    const int head = *s_head;
    const int olen = olens[b];
    const uint8_t* arow = amax + ((size_t)b * H + head) * L;
    for (int l = tid; l < olen; l += 256)
        atomicAdd(&hist[arow[l]], 1);
    __syncthreads();

    for (int t = tid; t < T; t += 256)
        out[b * T + t] = hist[t];
}

// ---------------------------------------------------------------------------
// Fused cooperative kernel: rowscan -> grid sync -> blocks 0..31 do finals.
__global__ __launch_bounds__(256, 3) void k_fused(const float* __restrict__ att,
                                                  const int* __restrict__ ilens,
                                                  const int* __restrict__ olens,
                                                  uint8_t* __restrict__ amax,
                                                  double* __restrict__ partial,
                                                  int* __restrict__ out) {
    __shared__ double sh[16];
    __shared__ double shd[H];
    __shared__ int s_head;
    __shared__ int hist[T];

    rowscan_body(att, ilens, amax, partial, sh);
    cg::this_grid().sync();
    if (blockIdx.x < B)
        final_body(amax, olens, partial, out, blockIdx.x, shd, &s_head, hist);
}

// Fallback pair (non-cooperative path)
__global__ __launch_bounds__(256, 3) void k_rowscan(const float* __restrict__ att,
                                                    const int* __restrict__ ilens,
                                                    uint8_t* __restrict__ amax,
                                                    double* __restrict__ partial) {
    __shared__ double sh[16];
    rowscan_body(att, ilens, amax, partial, sh);
}

__global__ __launch_bounds__(256) void k_final(const uint8_t* __restrict__ amax,
                                               const int* __restrict__ olens,
                                               const double* __restrict__ partial,
                                               int* __restrict__ out) {
    __shared__ double shd[H];
    __shared__ int s_head;
    __shared__ int hist[T];
    final_body(amax, olens, partial, out, blockIdx.x, shd, &s_head, hist);
}

// ---------------------------------------------------------------------------
extern "C" void kernel_launch(void* const* d_in, const int* in_sizes, int n_in,
                              void* d_out, int out_size, void* d_ws, size_t ws_size,
                              hipStream_t stream) {
    const float* att = (const float*)d_in[0];
    const int* ilens = (const int*)d_in[1];
    const int* olens = (const int*)d_in[2];
    int* out = (int*)d_out;

    char* ws = (char*)d_ws;
    double* partial = (double*)(ws);            // 768 * 8 = 6144 B
    uint8_t* amax   = (uint8_t*)(ws + 8192);    // 614400 B

    int dev = 0;
    hipGetDevice(&dev);
    int coop = 0;
    hipDeviceGetAttribute(&coop, hipDeviceAttributeCooperativeLaunch, dev);

    if (coop) {
        void* args[] = {(void*)&att, (void*)&ilens, (void*)&olens,
                        (void*)&amax, (void*)&partial, (void*)&out};
        hipLaunchCooperativeKernel((const void*)k_fused, dim3(GRID), dim3(256),
                                   args, 0, stream);
    } else {
        k_rowscan<<<GRID, 256, 0, stream>>>(att, ilens, amax, partial);
        k_final<<<B, 256, 0, stream>>>(amax, olens, partial, out);
    }
}

// Round 6
// 136.250 us; speedup vs baseline: 1.3012x; 1.3012x over previous
//
#include <hip/hip_runtime.h>
#include <cfloat>
#include <cstdint>

// Problem constants (match reference)
constexpr int B = 32, H = 24, L = 800, T = 200;
constexpr int ROWS = B * H * L;      // 614400
constexpr int GRID = 768;            // 3 blocks/CU exactly; 800 rows per block
constexpr int TPB = 50;              // tasks per block (16 rows per task)
constexpr int F4_ROW = T / 4;        // 50 float4 per row

typedef float v4f __attribute__((ext_vector_type(4)));

__device__ inline v4f ntl(const v4f* p) { return __builtin_nontemporal_load(p); }

// ws layout:
//   [0,8)          uint32 done_counter (zeroed via 4B hipMemsetAsync each call)
//   [64, 64+6144)  double partial[768]
//   [8192, +ROWS)  uint8 amax[ROWS]

__device__ inline void upd(float v, int t, int ilen,
                           float& rmax, float& bv, int& bi) {
    rmax = fmaxf(rmax, v);
    // values are uniform [0,1) -> -1.0f is a safe "-inf" sentinel; every lane's
    // first float4 is at t<64<=ilen so bv ends >=0 and sentinels never win.
    const float vm = (t < ilen) ? v : -1.0f;
    if (vm > bv) { bv = vm; bi = t; }   // strict '>' + increasing t = first occurrence
}

__device__ inline void upd4(const v4f v, int t0, int ilen,
                            float& rmax, float& bv, int& bi) {
    upd(v.x, t0 + 0, ilen, rmax, bv, bi);
    upd(v.y, t0 + 1, ilen, rmax, bv, bi);
    upd(v.z, t0 + 2, ilen, rmax, bv, bi);
    upd(v.w, t0 + 3, ilen, rmax, bv, bi);
}

// ---------------------------------------------------------------------------
// Single fused kernel. Each block covers rows [bid*800, bid*800+800) ->
// exactly one (b, h): b = bid/24, h = bid%24; ilen is block-uniform.
// After the streaming scan, blocks signal a device-scope counter; blocks 0..31
// spin until all 768 have signaled, then run head-select + histogram for batch
// element fb == bid. All 768 blocks are co-resident (3/CU) -> no deadlock.
__global__ __launch_bounds__(256, 3) void k_fused(const float* __restrict__ att,
                                                  const int* __restrict__ ilens,
                                                  const int* __restrict__ olens,
                                                  uint8_t* __restrict__ amax,
                                                  double* __restrict__ partial,
                                                  uint32_t* __restrict__ cnt,
                                                  int* __restrict__ out) {
    const int tid = threadIdx.x;
    const int grp = tid >> 4;          // 16 groups (rows) per task
    const int j   = tid & 15;          // lane within group
    const int bid = blockIdx.x;
    const int b   = bid / H;           // block-uniform batch (rowscan phase)
    const int ilen = ilens[b];         // scalar

    const int row0 = bid * 800 + grp;
    const v4f* p = (const v4f*)att + (size_t)row0 * F4_ROW;

    double acc = 0.0;                  // group leaders (j==0) only

    // prefetch task 0
    v4f c0 = ntl(p + j), c1 = ntl(p + j + 16), c2 = ntl(p + j + 32), c3{};
    if (j < 2) c3 = ntl(p + 48 + j);

    #pragma unroll 2
    for (int it = 0; it < TPB; ++it) {
        const v4f* pn = p + 16 * F4_ROW;
        v4f n0{}, n1{}, n2{}, n3{};
        if (it + 1 < TPB) {            // prefetch next task
            n0 = ntl(pn + j); n1 = ntl(pn + j + 16); n2 = ntl(pn + j + 32);
            if (j < 2) n3 = ntl(pn + 48 + j);
        }

        float rmax = -FLT_MAX, bv = -FLT_MAX;
        int bi = 0;
        upd4(c0, 4 * j,       ilen, rmax, bv, bi);
        upd4(c1, 4 * j + 64,  ilen, rmax, bv, bi);
        upd4(c2, 4 * j + 128, ilen, rmax, bv, bi);
        if (j < 2) upd4(c3, 192 + 4 * j, ilen, rmax, bv, bi);

        // reduce within the 16-lane group
        #pragma unroll
        for (int off = 8; off >= 1; off >>= 1) {
            const float ov = __shfl_xor(bv, off);
            const int   oi = __shfl_xor(bi, off);
            rmax = fmaxf(rmax, __shfl_xor(rmax, off));
            if (ov > bv || (ov == bv && oi < bi)) { bv = ov; bi = oi; }
        }

        if (j == 0) {
            amax[row0 + it * 16] = (uint8_t)bi;
            acc += (double)rmax;
        }

        c0 = n0; c1 = n1; c2 = n2; c3 = n3;
        p = pn;
    }

    // block reduce: 16 group-leader accs, fixed order -> deterministic
    __shared__ double sh[16];
    if (j == 0) sh[grp] = acc;
    __syncthreads();                   // also orders this block's amax stores
    if (tid == 0) {
        double s = 0.0;
        #pragma unroll
        for (int i = 0; i < 16; ++i) s += sh[i];
        partial[bid] = s;
        __threadfence();               // flush partial + amax device-wide
        __hip_atomic_fetch_add(cnt, 1u, __ATOMIC_RELEASE,
                               __HIP_MEMORY_SCOPE_AGENT);
    }

    if (bid >= B) return;              // only blocks 0..31 do the final phase

    const int fb = bid;                // finalist batch element (BUGFIX: was b)

    // ---- wait for all 768 blocks ----
    if (tid == 0) {
        while (__hip_atomic_load(cnt, __ATOMIC_ACQUIRE,
                                 __HIP_MEMORY_SCOPE_AGENT) < (uint32_t)GRID) {
            __builtin_amdgcn_s_sleep(8);
        }
    }
    __syncthreads();                   // publish acquired state to whole block

    // head selection: fixed-tree reduce over 768 partials, deterministic
    __shared__ double shd[H];
    __shared__ int s_head;
    __shared__ int hist[T];

    if (tid < 192) {                   // 8 threads per head
        const int h = tid >> 3, k = tid & 7;
        double s = 0.0;
        #pragma unroll
        for (int m = 0; m < 4; ++m)
            s += partial[(size_t)(k * 4 + m) * H + h];   // partial[bb*24 + h]
        s += __shfl_xor(s, 1);
        s += __shfl_xor(s, 2);
        s += __shfl_xor(s, 4);
        if (k == 0) shd[h] = s;
    }
    for (int t = tid; t < T; t += 256) hist[t] = 0;
    __syncthreads();

    if (tid == 0) {
        double best = shd[0]; int bh = 0;
        for (int h = 1; h < H; ++h)
            if (shd[h] > best) { best = shd[h]; bh = h; }
        s_head = bh;
    }
    __syncthreads();

    const int head = s_head;
    const int olen = olens[fb];
    const uint8_t* arow = amax + ((size_t)fb * H + head) * L;
    for (int l = tid; l < olen; l += 256)
        atomicAdd(&hist[arow[l]], 1);
    __syncthreads();

    for (int t = tid; t < T; t += 256)
        out[fb * T + t] = hist[t];
}

// ---------------------------------------------------------------------------
extern "C" void kernel_launch(void* const* d_in, const int* in_sizes, int n_in,
                              void* d_out, int out_size, void* d_ws, size_t ws_size,
                              hipStream_t stream) {
    const float* att = (const float*)d_in[0];
    const int* ilens = (const int*)d_in[1];
    const int* olens = (const int*)d_in[2];
    int* out = (int*)d_out;

    char* ws = (char*)d_ws;
    uint32_t* cnt   = (uint32_t*)(ws);          // 4 B
    double* partial = (double*)(ws + 64);       // 768 * 8 = 6144 B
    uint8_t* amax   = (uint8_t*)(ws + 8192);    // 614400 B

    // counter accumulates to 768 each call -> must start at 0 every call
    hipMemsetAsync(cnt, 0, sizeof(uint32_t), stream);

    k_fused<<<GRID, 256, 0, stream>>>(att, ilens, olens, amax, partial, cnt, out);
}

// Round 7
// 82.656 us; speedup vs baseline: 2.1448x; 1.6484x over previous
//
#include <hip/hip_runtime.h>
#include <cfloat>
#include <cstdint>

// Problem constants (match reference)
constexpr int B = 32, H = 24, L = 800, T = 200;
constexpr int GRID = 768;            // 3 blocks/CU exactly; 800 rows per block
constexpr int TPB = 50;              // tasks per block (16 rows per task)
constexpr int F4_ROW = T / 4;        // 50 float4 per row

typedef float v4f __attribute__((ext_vector_type(4)));

__device__ inline v4f ntl(const v4f* p) { return __builtin_nontemporal_load(p); }

// ws layout:
//   [0, 6144)          double partial[768]   (written unconditionally)
//   [8192, +768*200*4) int hist_all[768][200] (written unconditionally)

__device__ inline void upd(float v, int t, int ilen,
                           float& rmax, float& bv, int& bi) {
    rmax = fmaxf(rmax, v);
    // values are uniform [0,1) -> -1.0f is a safe "-inf" sentinel; every lane's
    // first float4 is at t<64<=ilen so bv ends >=0 and sentinels never win.
    const float vm = (t < ilen) ? v : -1.0f;
    if (vm > bv) { bv = vm; bi = t; }   // strict '>' + increasing t = first occurrence
}

__device__ inline void upd4(const v4f v, int t0, int ilen,
                            float& rmax, float& bv, int& bi) {
    upd(v.x, t0 + 0, ilen, rmax, bv, bi);
    upd(v.y, t0 + 1, ilen, rmax, bv, bi);
    upd(v.z, t0 + 2, ilen, rmax, bv, bi);
    upd(v.w, t0 + 3, ilen, rmax, bv, bi);
}

// ---------------------------------------------------------------------------
// Each block covers rows [bid*800, bid*800+800) -> exactly one (b, h):
//   b = bid/24, h = bid%24. ilen and olen are block-uniform. The block builds
//   the COMPLETE duration histogram for its (b,h) in LDS during the scan
//   (hidden under HBM latency) plus the diag partial sum.
__global__ __launch_bounds__(256, 3) void k_rowscan(const float* __restrict__ att,
                                                    const int* __restrict__ ilens,
                                                    const int* __restrict__ olens,
                                                    int* __restrict__ hist_all,
                                                    double* __restrict__ partial) {
    const int tid = threadIdx.x;
    const int grp = tid >> 4;          // 16 groups (rows) per task
    const int j   = tid & 15;          // lane within group
    const int bid = blockIdx.x;
    const int b   = bid / H;           // block-uniform batch
    const int ilen = ilens[b];         // scalar
    const int olen = olens[b];         // scalar

    __shared__ int hist[T];
    __shared__ double sh[16];
    for (int t = tid; t < T; t += 256) hist[t] = 0;
    __syncthreads();

    const int row0 = bid * 800 + grp;
    const v4f* p = (const v4f*)att + (size_t)row0 * F4_ROW;

    double acc = 0.0;                  // group leaders (j==0) only

    // prefetch task 0
    v4f c0 = ntl(p + j), c1 = ntl(p + j + 16), c2 = ntl(p + j + 32), c3{};
    if (j < 2) c3 = ntl(p + 48 + j);

    #pragma unroll 2
    for (int it = 0; it < TPB; ++it) {
        const v4f* pn = p + 16 * F4_ROW;
        v4f n0{}, n1{}, n2{}, n3{};
        if (it + 1 < TPB) {            // prefetch next task
            n0 = ntl(pn + j); n1 = ntl(pn + j + 16); n2 = ntl(pn + j + 32);
            if (j < 2) n3 = ntl(pn + 48 + j);
        }

        float rmax = -FLT_MAX, bv = -FLT_MAX;
        int bi = 0;
        upd4(c0, 4 * j,       ilen, rmax, bv, bi);
        upd4(c1, 4 * j + 64,  ilen, rmax, bv, bi);
        upd4(c2, 4 * j + 128, ilen, rmax, bv, bi);
        if (j < 2) upd4(c3, 192 + 4 * j, ilen, rmax, bv, bi);

        // reduce within the 16-lane group
        #pragma unroll
        for (int off = 8; off >= 1; off >>= 1) {
            const float ov = __shfl_xor(bv, off);
            const int   oi = __shfl_xor(bi, off);
            rmax = fmaxf(rmax, __shfl_xor(rmax, off));
            if (ov > bv || (ov == bv && oi < bi)) { bv = ov; bi = oi; }
        }

        if (j == 0) {
            const int l = it * 16 + grp;           // output frame index
            if (l < olen) atomicAdd(&hist[bi], 1); // LDS atomic, deterministic
            acc += (double)rmax;
        }

        c0 = n0; c1 = n1; c2 = n2; c3 = n3;
        p = pn;
    }

    // block reduce: 16 group-leader accs, fixed order -> deterministic
    if (j == 0) sh[grp] = acc;
    __syncthreads();                   // hist complete + sh visible
    if (tid == 0) {
        double s = 0.0;
        #pragma unroll
        for (int i = 0; i < 16; ++i) s += sh[i];
        partial[bid] = s;
    }

    // dump this (b,h)'s full histogram
    int* hout = hist_all + (size_t)bid * T;
    for (int t = tid; t < T; t += 256) hout[t] = hist[t];
}

// ---------------------------------------------------------------------------
// Head selection (fixed-tree reduce over 768 partials, deterministic) + copy
// the precomputed histogram of (b, head) to out. One block per batch element.
__global__ __launch_bounds__(256) void k_final(const int* __restrict__ hist_all,
                                               const double* __restrict__ partial,
                                               int* __restrict__ out) {
    __shared__ double shd[H];
    __shared__ int s_head;
    const int tid = threadIdx.x;
    const int b = blockIdx.x;

    if (tid < 192) {                   // 8 threads per head
        const int h = tid >> 3, k = tid & 7;
        double s = 0.0;
        #pragma unroll
        for (int m = 0; m < 4; ++m)
            s += partial[(size_t)(k * 4 + m) * H + h];   // partial[bb*24 + h]
        s += __shfl_xor(s, 1);
        s += __shfl_xor(s, 2);
        s += __shfl_xor(s, 4);
        if (k == 0) shd[h] = s;
    }
    __syncthreads();

    if (tid == 0) {
        double best = shd[0]; int bh = 0;
        for (int h = 1; h < H; ++h)
            if (shd[h] > best) { best = shd[h]; bh = h; }
        s_head = bh;
    }
    __syncthreads();

    const int head = s_head;
    const int* hsrc = hist_all + ((size_t)b * H + head) * T;
    if (tid < T) out[b * T + tid] = hsrc[tid];
}

// ---------------------------------------------------------------------------
extern "C" void kernel_launch(void* const* d_in, const int* in_sizes, int n_in,
                              void* d_out, int out_size, void* d_ws, size_t ws_size,
                              hipStream_t stream) {
    const float* att = (const float*)d_in[0];
    const int* ilens = (const int*)d_in[1];
    const int* olens = (const int*)d_in[2];
    int* out = (int*)d_out;

    char* ws = (char*)d_ws;
    double* partial = (double*)(ws);            // 768 * 8 = 6144 B
    int* hist_all   = (int*)(ws + 8192);        // 768 * 200 * 4 = 614400 B

    // every partial/hist_all slot is written unconditionally -> no memset
    k_rowscan<<<GRID, 256, 0, stream>>>(att, ilens, olens, hist_all, partial);
    k_final<<<B, 256, 0, stream>>>(hist_all, partial, out);
}